// Round 2
// baseline (326.334 us; speedup 1.0000x reference)
//
#include <hip/hip_runtime.h>
#include <math.h>

#define FACE_W 256
#define CH 32
#define BATCH 2
#define OUT_H (2 * FACE_W)            // 512
#define OUT_W (4 * FACE_W)            // 1024
#define N_PIX (OUT_H * OUT_W)         // 524288
#define PLANE (FACE_W * FACE_W)       // 65536 elems
#define FACE_STRIDE (CH * PLANE)      // 2097152 elems (2^21)
#define BATCH_STRIDE (6 * FACE_STRIDE)
#define OUT_PLANE (OUT_H * OUT_W)
#define REC_BYTES ((size_t)N_PIX * 16)

// ---------------- Kernel 1: per-pixel grid math (pixel-only, no b/c dep) ----
// Record: {off00 = face*FACE_STRIDE + y0*256 + x0, bits(wx), bits(wy), 0}.
// x0/y0 recoverable as off00&255 / (off00>>8)&255 since FACE_STRIDE is a
// multiple of 2^16. fp64 trig keeps the face decision far from boundaries
// (verified: absmax 0.0156 vs threshold 0.096 in round 1).
__global__ __launch_bounds__(256) void grid_kernel(uint4* __restrict__ rec) {
    int pix = blockIdx.x * blockDim.x + threadIdx.x;
    if (pix >= N_PIX) return;
    int xx = pix & (OUT_W - 1);
    int yy = pix >> 10;

    const double PI = 3.14159265358979323846;
    double theta = (2.0 * (xx + 0.5) / OUT_W - 1.0) * PI;
    double phi   = (2.0 * (yy + 0.5) / OUT_H - 1.0) * (PI * 0.5);
    double cph = cos(phi);
    double sx = cph * cos(theta);
    double sy = cph * sin(theta);
    double sz = sin(phi);
    double ax = fabs(sx), ay = fabs(sy), az = fabs(sz);

    const double EPS = 1e-9;
    int face;
    double u, v;
    if (ax >= ay && ax >= az) {
        face = (sx >= 0.0) ? 0 : 1;
        double d = fmax(ax, EPS);
        u = ((face == 0) ? sy : -sy) / d;
        v = sz / d;
    } else if (ay >= az) {
        face = (sy >= 0.0) ? 2 : 3;
        double d = fmax(ay, EPS);
        u = ((face == 2) ? -sx : sx) / d;
        v = sz / d;
    } else {
        face = (sz >= 0.0) ? 4 : 5;
        double d = fmax(az, EPS);
        u = sy / d;
        v = ((face == 4) ? -sx : sx) / d;
    }

    float px = (float)((u + 1.0) * 0.5 * (FACE_W - 1));
    float py = (float)((v + 1.0) * 0.5 * (FACE_W - 1));
    float fx0 = floorf(px), fy0 = floorf(py);
    float wx = px - fx0, wy = py - fy0;
    int x0 = min(max((int)fx0, 0), FACE_W - 1);
    int y0 = min(max((int)fy0, 0), FACE_W - 1);

    unsigned off00 = (unsigned)face * FACE_STRIDE + (unsigned)(y0 * FACE_W + x0);
    rec[pix] = make_uint4(off00, __float_as_uint(wx), __float_as_uint(wy), 0u);
}

// ---------------- Kernel 2: gather + blend, batched loads -------------------
// Thread = (pixel, b). 32 channels per thread in groups of 8: issue all 32
// corner loads for a group before consuming -> 32 outstanding loads/wave
// (vs ~4 in round 1's 32-VGPR kernel). Writes stay perfectly coalesced.
__global__ __launch_bounds__(256, 4) void sample_kernel(
    const float* __restrict__ in, const uint4* __restrict__ rec,
    float* __restrict__ out) {
    int pix = blockIdx.x * blockDim.x + threadIdx.x;
    int b = blockIdx.y;

    uint4 r = rec[pix];
    unsigned off00 = r.x;
    float wx = __uint_as_float(r.y);
    float wy = __uint_as_float(r.z);
    int x0 = off00 & 255;
    int y0 = (off00 >> 8) & 255;
    int dx  = (x0 < FACE_W - 1) ? 1 : 0;
    int dyr = (y0 < FACE_W - 1) ? FACE_W : 0;

    float w00 = (1.0f - wx) * (1.0f - wy);
    float w10 = wx * (1.0f - wy);
    float w01 = (1.0f - wx) * wy;
    float w11 = wx * wy;

    const float* base = in + (size_t)b * BATCH_STRIDE + off00;
    float* ob = out + (size_t)b * CH * OUT_PLANE + pix;

    #pragma unroll 1
    for (int cg = 0; cg < CH / 8; ++cg) {
        float v00[8], v10[8], v01[8], v11[8];
        #pragma unroll
        for (int j = 0; j < 8; ++j) {
            const float* p = base + (size_t)(cg * 8 + j) * PLANE;
            v00[j] = p[0];
            v10[j] = p[dx];
            v01[j] = p[dyr];
            v11[j] = p[dx + dyr];
        }
        #pragma unroll
        for (int j = 0; j < 8; ++j) {
            ob[(size_t)(cg * 8 + j) * OUT_PLANE] =
                v00[j] * w00 + v10[j] * w10 + v01[j] * w01 + v11[j] * w11;
        }
    }
}

// ---------------- Fallback: round-1 fused kernel (if ws too small) ----------
__global__ __launch_bounds__(256) void cube2equi_fused(
    const float* __restrict__ in, float* __restrict__ out) {
    int pix = blockIdx.x * blockDim.x + threadIdx.x;
    if (pix >= N_PIX) return;
    int xx = pix & (OUT_W - 1);
    int yy = pix >> 10;

    const double PI = 3.14159265358979323846;
    double theta = (2.0 * (xx + 0.5) / OUT_W - 1.0) * PI;
    double phi   = (2.0 * (yy + 0.5) / OUT_H - 1.0) * (PI * 0.5);
    double cph = cos(phi);
    double sx = cph * cos(theta);
    double sy = cph * sin(theta);
    double sz = sin(phi);
    double ax = fabs(sx), ay = fabs(sy), az = fabs(sz);

    const double EPS = 1e-9;
    int face;
    double u, v;
    if (ax >= ay && ax >= az) {
        face = (sx >= 0.0) ? 0 : 1;
        double d = fmax(ax, EPS);
        u = ((face == 0) ? sy : -sy) / d;
        v = sz / d;
    } else if (ay >= az) {
        face = (sy >= 0.0) ? 2 : 3;
        double d = fmax(ay, EPS);
        u = ((face == 2) ? -sx : sx) / d;
        v = sz / d;
    } else {
        face = (sz >= 0.0) ? 4 : 5;
        double d = fmax(az, EPS);
        u = sy / d;
        v = ((face == 4) ? -sx : sx) / d;
    }

    float px = (float)((u + 1.0) * 0.5 * (FACE_W - 1));
    float py = (float)((v + 1.0) * 0.5 * (FACE_W - 1));
    float fx0 = floorf(px), fy0 = floorf(py);
    float wx = px - fx0, wy = py - fy0;
    int x0 = min(max((int)fx0, 0), FACE_W - 1);
    int x1 = min(max((int)fx0 + 1, 0), FACE_W - 1);
    int y0 = min(max((int)fy0, 0), FACE_W - 1);
    int y1 = min(max((int)fy0 + 1, 0), FACE_W - 1);

    float w00 = (1.0f - wx) * (1.0f - wy);
    float w10 = wx * (1.0f - wy);
    float w01 = (1.0f - wx) * wy;
    float w11 = wx * wy;

    int o00 = y0 * FACE_W + x0;
    int o10 = y0 * FACE_W + x1;
    int o01 = y1 * FACE_W + x0;
    int o11 = y1 * FACE_W + x1;

    const float* fbase = in + (size_t)face * FACE_STRIDE;
    size_t outPix = (size_t)pix;

    for (int b = 0; b < BATCH; ++b) {
        const float* bb = fbase + (size_t)b * BATCH_STRIDE;
        float* obp = out + (size_t)b * CH * OUT_PLANE + outPix;
        #pragma unroll 4
        for (int c = 0; c < CH; ++c) {
            const float* p = bb + (size_t)c * PLANE;
            obp[(size_t)c * OUT_PLANE] = p[o00] * w00 + p[o10] * w10 +
                                         p[o01] * w01 + p[o11] * w11;
        }
    }
}

extern "C" void kernel_launch(void* const* d_in, const int* in_sizes, int n_in,
                              void* d_out, int out_size, void* d_ws, size_t ws_size,
                              hipStream_t stream) {
    const float* in = (const float*)d_in[0];
    float* out = (float*)d_out;

    if (ws_size >= REC_BYTES) {
        uint4* rec = (uint4*)d_ws;
        grid_kernel<<<N_PIX / 256, 256, 0, stream>>>(rec);
        dim3 grid(N_PIX / 256, BATCH);
        sample_kernel<<<grid, 256, 0, stream>>>(in, rec, out);
    } else {
        cube2equi_fused<<<N_PIX / 256, 256, 0, stream>>>(in, out);
    }
}

// Round 3
// 286.648 us; speedup vs baseline: 1.1384x; 1.1384x over previous
//
#include <hip/hip_runtime.h>
#include <math.h>

#define FACE_W 256
#define CH 32
#define BATCH 2
#define OUT_H (2 * FACE_W)            // 512
#define OUT_W (4 * FACE_W)            // 1024
#define N_PIX (OUT_H * OUT_W)         // 524288 = 2^19
#define PLANE (FACE_W * FACE_W)       // 65536
#define FACE_STRIDE (CH * PLANE)      // 2^21
#define BATCH_STRIDE (6 * FACE_STRIDE)
#define OUT_PLANE (OUT_H * OUT_W)

#define TRANS_BYTES ((size_t)BATCH * 6 * PLANE * CH * 4)   // 96 MiB
#define REC_BYTES   ((size_t)N_PIX * 16)                   // 8 MiB

// ---------------- Kernel A: transpose (b,f,C,W,W) -> (b,f,W,W,C) ------------
// LDS-tiled: 64 pixels x 32 channels per block; both global phases fully
// coalesced (256 B contiguous per wave instruction).
__global__ __launch_bounds__(256) void transpose_kernel(
    const float* __restrict__ in, float* __restrict__ out_t) {
    __shared__ float tile[64][CH + 1];          // +1 pad: conflict-free
    int bf   = blockIdx.x >> 10;                // (b*6+face) in [0,12)
    int p0   = (blockIdx.x & 1023) << 6;        // pixel tile base
    int tid  = threadIdx.x;

    const float* src = in + (size_t)bf * FACE_STRIDE + p0;
    int pl = tid & 63, c0 = tid >> 6;           // read: lanes sweep pixels
    #pragma unroll
    for (int c = c0; c < CH; c += 4)
        tile[pl][c] = src[(size_t)c * PLANE + pl];
    __syncthreads();

    float* dst = out_t + ((size_t)bf * PLANE + p0) * CH;
    int cl = tid & 31, pl2 = tid >> 5;          // write: lanes sweep channels
    #pragma unroll
    for (int k = 0; k < 8; ++k) {
        int p = pl2 + 8 * k;
        dst[(size_t)p * CH + cl] = tile[p][cl];
    }
}

// ---------------- Kernel B: per-pixel grid math (fp64 -> 16 B record) -------
// fp64 keeps the face decision far from cube-edge boundaries (round-1
// verified: absmax 0.0156 vs threshold 0.096).
__global__ __launch_bounds__(256) void grid_kernel(uint4* __restrict__ rec) {
    int pix = blockIdx.x * blockDim.x + threadIdx.x;
    if (pix >= N_PIX) return;
    int xx = pix & (OUT_W - 1);
    int yy = pix >> 10;

    const double PI = 3.14159265358979323846;
    double theta = (2.0 * (xx + 0.5) / OUT_W - 1.0) * PI;
    double phi   = (2.0 * (yy + 0.5) / OUT_H - 1.0) * (PI * 0.5);
    double cph = cos(phi);
    double sx = cph * cos(theta);
    double sy = cph * sin(theta);
    double sz = sin(phi);
    double ax = fabs(sx), ay = fabs(sy), az = fabs(sz);

    const double EPS = 1e-9;
    int face;
    double u, v;
    if (ax >= ay && ax >= az) {
        face = (sx >= 0.0) ? 0 : 1;
        double d = fmax(ax, EPS);
        u = ((face == 0) ? sy : -sy) / d;
        v = sz / d;
    } else if (ay >= az) {
        face = (sy >= 0.0) ? 2 : 3;
        double d = fmax(ay, EPS);
        u = ((face == 2) ? -sx : sx) / d;
        v = sz / d;
    } else {
        face = (sz >= 0.0) ? 4 : 5;
        double d = fmax(az, EPS);
        u = sy / d;
        v = ((face == 4) ? -sx : sx) / d;
    }

    float px = (float)((u + 1.0) * 0.5 * (FACE_W - 1));
    float py = (float)((v + 1.0) * 0.5 * (FACE_W - 1));
    float fx0 = floorf(px), fy0 = floorf(py);
    float wx = px - fx0, wy = py - fy0;
    int x0 = min(max((int)fx0, 0), FACE_W - 1);
    int y0 = min(max((int)fy0, 0), FACE_W - 1);

    unsigned off00 = ((unsigned)face << 21) | (unsigned)(y0 * FACE_W + x0);
    rec[pix] = make_uint4(off00, __float_as_uint(wx), __float_as_uint(wy), 0u);
}

// ---------------- Kernel C: gather+blend on channel-last data ---------------
// 8 lanes per (pixel,b); each lane owns 4 consecutive channels -> every
// corner gather is a 16 B contiguous float4 per lane. A wave touches
// 8 pixels x 128 B = ~16 cache lines per load instruction, INDEPENDENT of
// the polar scatter pattern (vs up to 64 lines in the pixel-per-lane form).
__global__ __launch_bounds__(256) void sample_cl_kernel(
    const float* __restrict__ in_t, const uint4* __restrict__ rec,
    float* __restrict__ out) {
    unsigned g = blockIdx.x * blockDim.x + threadIdx.x;
    int cg  = g & 7;               // channel group (4 ch each)
    unsigned pb = g >> 3;
    int pix = pb & (N_PIX - 1);
    int b   = pb >> 19;

    uint4 r = rec[pix];
    unsigned off00 = r.x;
    float wx = __uint_as_float(r.y);
    float wy = __uint_as_float(r.z);
    int face   = off00 >> 21;
    int pix16  = off00 & 0xFFFF;
    int x0 = off00 & 255;
    int y0 = (off00 >> 8) & 255;
    int dxE = (x0 < FACE_W - 1) ? CH : 0;            // +1 in x  -> +32 floats
    int dyE = (y0 < FACE_W - 1) ? FACE_W * CH : 0;   // +1 in y  -> +8192

    float w00 = (1.0f - wx) * (1.0f - wy);
    float w10 = wx * (1.0f - wy);
    float w01 = (1.0f - wx) * wy;
    float w11 = wx * wy;

    const float* src = in_t + ((size_t)(b * 6 + face) * PLANE + pix16) * CH + cg * 4;
    float4 v00 = *(const float4*)(src);
    float4 v10 = *(const float4*)(src + dxE);
    float4 v01 = *(const float4*)(src + dyE);
    float4 v11 = *(const float4*)(src + dxE + dyE);

    float* ob = out + ((size_t)b * CH + cg * 4) * OUT_PLANE + pix;
    ob[0 * OUT_PLANE] = v00.x * w00 + v10.x * w10 + v01.x * w01 + v11.x * w11;
    ob[1 * OUT_PLANE] = v00.y * w00 + v10.y * w10 + v01.y * w01 + v11.y * w11;
    ob[2 * OUT_PLANE] = v00.z * w00 + v10.z * w10 + v01.z * w01 + v11.z * w11;
    ob[3 * OUT_PLANE] = v00.w * w00 + v10.w * w10 + v01.w * w01 + v11.w * w11;
}

// ---------------- Fallback 1 (round 2): record + batched dword gathers ------
__global__ __launch_bounds__(256, 4) void sample_kernel(
    const float* __restrict__ in, const uint4* __restrict__ rec,
    float* __restrict__ out) {
    int pix = blockIdx.x * blockDim.x + threadIdx.x;
    int b = blockIdx.y;

    uint4 r = rec[pix];
    unsigned off00i = (r.x >> 21) * FACE_STRIDE + (r.x & 0xFFFF);
    float wx = __uint_as_float(r.y);
    float wy = __uint_as_float(r.z);
    int x0 = r.x & 255;
    int y0 = (r.x >> 8) & 255;
    int dx  = (x0 < FACE_W - 1) ? 1 : 0;
    int dyr = (y0 < FACE_W - 1) ? FACE_W : 0;

    float w00 = (1.0f - wx) * (1.0f - wy);
    float w10 = wx * (1.0f - wy);
    float w01 = (1.0f - wx) * wy;
    float w11 = wx * wy;

    const float* base = in + (size_t)b * BATCH_STRIDE + off00i;
    float* ob = out + (size_t)b * CH * OUT_PLANE + pix;

    #pragma unroll 1
    for (int cg = 0; cg < CH / 8; ++cg) {
        float v00[8], v10[8], v01[8], v11[8];
        #pragma unroll
        for (int j = 0; j < 8; ++j) {
            const float* p = base + (size_t)(cg * 8 + j) * PLANE;
            v00[j] = p[0];
            v10[j] = p[dx];
            v01[j] = p[dyr];
            v11[j] = p[dx + dyr];
        }
        #pragma unroll
        for (int j = 0; j < 8; ++j) {
            ob[(size_t)(cg * 8 + j) * OUT_PLANE] =
                v00[j] * w00 + v10[j] * w10 + v01[j] * w01 + v11[j] * w11;
        }
    }
}

// ---------------- Fallback 2 (round 1): fully fused -------------------------
__global__ __launch_bounds__(256) void cube2equi_fused(
    const float* __restrict__ in, float* __restrict__ out) {
    int pix = blockIdx.x * blockDim.x + threadIdx.x;
    if (pix >= N_PIX) return;
    int xx = pix & (OUT_W - 1);
    int yy = pix >> 10;

    const double PI = 3.14159265358979323846;
    double theta = (2.0 * (xx + 0.5) / OUT_W - 1.0) * PI;
    double phi   = (2.0 * (yy + 0.5) / OUT_H - 1.0) * (PI * 0.5);
    double cph = cos(phi);
    double sx = cph * cos(theta);
    double sy = cph * sin(theta);
    double sz = sin(phi);
    double ax = fabs(sx), ay = fabs(sy), az = fabs(sz);

    const double EPS = 1e-9;
    int face;
    double u, v;
    if (ax >= ay && ax >= az) {
        face = (sx >= 0.0) ? 0 : 1;
        double d = fmax(ax, EPS);
        u = ((face == 0) ? sy : -sy) / d;
        v = sz / d;
    } else if (ay >= az) {
        face = (sy >= 0.0) ? 2 : 3;
        double d = fmax(ay, EPS);
        u = ((face == 2) ? -sx : sx) / d;
        v = sz / d;
    } else {
        face = (sz >= 0.0) ? 4 : 5;
        double d = fmax(az, EPS);
        u = sy / d;
        v = ((face == 4) ? -sx : sx) / d;
    }

    float px = (float)((u + 1.0) * 0.5 * (FACE_W - 1));
    float py = (float)((v + 1.0) * 0.5 * (FACE_W - 1));
    float fx0 = floorf(px), fy0 = floorf(py);
    float wx = px - fx0, wy = py - fy0;
    int x0 = min(max((int)fx0, 0), FACE_W - 1);
    int x1 = min(max((int)fx0 + 1, 0), FACE_W - 1);
    int y0 = min(max((int)fy0, 0), FACE_W - 1);
    int y1 = min(max((int)fy0 + 1, 0), FACE_W - 1);

    float w00 = (1.0f - wx) * (1.0f - wy);
    float w10 = wx * (1.0f - wy);
    float w01 = (1.0f - wx) * wy;
    float w11 = wx * wy;

    int o00 = y0 * FACE_W + x0;
    int o10 = y0 * FACE_W + x1;
    int o01 = y1 * FACE_W + x0;
    int o11 = y1 * FACE_W + x1;

    const float* fbase = in + (size_t)face * FACE_STRIDE;

    for (int b = 0; b < BATCH; ++b) {
        const float* bb = fbase + (size_t)b * BATCH_STRIDE;
        float* obp = out + (size_t)b * CH * OUT_PLANE + pix;
        #pragma unroll 4
        for (int c = 0; c < CH; ++c) {
            const float* p = bb + (size_t)c * PLANE;
            obp[(size_t)c * OUT_PLANE] = p[o00] * w00 + p[o10] * w10 +
                                         p[o01] * w01 + p[o11] * w11;
        }
    }
}

extern "C" void kernel_launch(void* const* d_in, const int* in_sizes, int n_in,
                              void* d_out, int out_size, void* d_ws, size_t ws_size,
                              hipStream_t stream) {
    const float* in = (const float*)d_in[0];
    float* out = (float*)d_out;

    if (ws_size >= TRANS_BYTES + REC_BYTES) {
        float* in_t = (float*)d_ws;
        uint4* rec = (uint4*)((char*)d_ws + TRANS_BYTES);
        grid_kernel<<<N_PIX / 256, 256, 0, stream>>>(rec);
        transpose_kernel<<<12 * (PLANE / 64), 256, 0, stream>>>(in, in_t);
        // total threads = N_PIX * BATCH * 8 = 2^23
        sample_cl_kernel<<<(N_PIX / 256) * BATCH * 8, 256, 0, stream>>>(in_t, rec, out);
    } else if (ws_size >= REC_BYTES) {
        uint4* rec = (uint4*)d_ws;
        grid_kernel<<<N_PIX / 256, 256, 0, stream>>>(rec);
        dim3 grid(N_PIX / 256, BATCH);
        sample_kernel<<<grid, 256, 0, stream>>>(in, rec, out);
    } else {
        cube2equi_fused<<<N_PIX / 256, 256, 0, stream>>>(in, out);
    }
}